// Round 2
// baseline (569.437 us; speedup 1.0000x reference)
//
#include <hip/hip_runtime.h>
#include <math.h>

// Problem constants (fixed by the reference): N=8, S=8192, C=1, K=1024, V=64
#define NS  65536            // N*S*C samples
#define KK  1024             // codebook size
#define VV  64               // vector length
#define SPB 64               // samples per block
#define NW  4                // waves per block
#define KCH (KK / NW)        // 256 codes per wave-chunk

// Output layout (flat, return order):
//   out0: (8,8192,1,64) = 4,194,304 floats @ 0
//   out1: (8,8192,1)    =    65,536 floats @ 4,194,304
//   out2: (8,8192,1)    =    65,536 floats @ 4,259,840
//   entropy: scalar     =         1 float  @ 4,325,376
#define OUT0_OFF 0
#define OUT1_OFF 4194304
#define OUT2_OFF 4259840
#define ENT_OFF  4325376

// ws layout: [0,4KB) histogram (1024 u32); [4KB,8KB) enorm (1024 f32)

__global__ void vq_prep(const float* __restrict__ emb, unsigned int* __restrict__ hist,
                        float* __restrict__ enorm) {
    int t = blockIdx.x * blockDim.x + threadIdx.x;   // 0..1023
    if (t < KK) {
        hist[t] = 0u;
        const float4* e4 = (const float4*)(emb + (size_t)t * VV);
        float s = 0.f;
        #pragma unroll
        for (int i = 0; i < VV / 4; ++i) {
            float4 f = e4[i];
            s = fmaf(f.x, f.x, s); s = fmaf(f.y, f.y, s);
            s = fmaf(f.z, f.z, s); s = fmaf(f.w, f.w, s);
        }
        enorm[t] = s;
    }
}

__global__ __launch_bounds__(256, 4) void vq_main(
    const float* __restrict__ x, const float* __restrict__ emb,
    const float* __restrict__ enorm, float* __restrict__ out0,
    float* __restrict__ out1, float* __restrict__ out2,
    unsigned int* __restrict__ hist)
{
    __shared__ float ls1[NW][SPB];
    __shared__ float ls2[NW][SPB];
    __shared__ int   li1[NW][SPB];
    __shared__ int   li2[NW][SPB];
    __shared__ int   lbest[SPB];

    const int tid  = threadIdx.x;
    const int wave = tid >> 6;        // 0..3  -> K chunk
    const int lane = tid & 63;        // 0..63 -> sample within block
    const int s0   = blockIdx.x * SPB;
    const int n    = s0 + lane;

    // Load this sample's 64-dim vector into registers.
    float rx[VV];
    {
        const float4* xv = (const float4*)(x + (size_t)n * VV);
        #pragma unroll
        for (int i = 0; i < VV / 4; ++i) {
            float4 f = xv[i];
            rx[4*i+0] = f.x; rx[4*i+1] = f.y; rx[4*i+2] = f.z; rx[4*i+3] = f.w;
        }
    }

    // Scan this wave's K-chunk, tracking top-2 (score = |e|^2 - 2 x.e).
    float s1 = INFINITY, s2 = INFINITY;
    int   i1 = 0, i2 = 0;
    const int kbase = wave * KCH;
    for (int k = kbase; k < kbase + KCH; ++k) {
        const float* ek = emb + (size_t)k * VV;   // wave-uniform address -> s_load
        float dot = 0.f;
        #pragma unroll
        for (int v = 0; v < VV; ++v) dot = fmaf(rx[v], ek[v], dot);
        float sc = fmaf(-2.f, dot, enorm[k]);
        if (sc < s1)      { s2 = s1; i2 = i1; s1 = sc; i1 = k; }
        else if (sc < s2) { s2 = sc; i2 = k; }
    }
    ls1[wave][lane] = s1; ls2[wave][lane] = s2;
    li1[wave][lane] = i1; li2[wave][lane] = i2;
    __syncthreads();

    if (wave == 0) {
        // Merge chunks 1..3 (ascending k order + strict < => first-min tie-break).
        #pragma unroll
        for (int w = 1; w < NW; ++w) {
            float a1 = ls1[w][lane], a2 = ls2[w][lane];
            int   b1 = li1[w][lane], b2 = li2[w][lane];
            if (a1 < s1)      { s2 = s1; i2 = i1; s1 = a1; i1 = b1; }
            else if (a1 < s2) { s2 = a1; i2 = b1; }
            if (a2 < s2)      { s2 = a2; i2 = b2; }
        }
        int best = i1;
        // Near-tie: re-rank the two candidates with exact fp64 true distances.
        if (s2 - s1 < 1e-5f) {
            const float* e1 = emb + (size_t)i1 * VV;
            const float* e2 = emb + (size_t)i2 * VV;
            double d1 = 0.0, d2 = 0.0;
            for (int v = 0; v < VV; ++v) {
                double t1 = (double)rx[v] - (double)e1[v];
                double t2 = (double)rx[v] - (double)e2[v];
                d1 += t1 * t1; d2 += t2 * t2;
            }
            if (d2 < d1 || (d2 == d1 && i2 < i1)) best = i2;
        }
        lbest[lane] = best;

        // out1/out2: direct fp32 squared distance to chosen codeword.
        const float* eb = emb + (size_t)best * VV;
        float d2s = 0.f;
        #pragma unroll
        for (int v = 0; v < VV; ++v) { float t = rx[v] - eb[v]; d2s = fmaf(t, t, d2s); }
        out1[n] = d2s;
        out2[n] = d2s;
        atomicAdd(&hist[best], 1u);
    }
    __syncthreads();

    // Cooperative coalesced out0 write: 256 threads x 16 contiguous floats.
    {
        int smp = tid >> 2;              // sample within block
        int v0  = (tid & 3) * 16;        // 16-float segment
        int row = lbest[smp];
        const float4* es = (const float4*)(emb + (size_t)row * VV + v0);
        float4*       od = (float4*)(out0 + (size_t)(s0 + smp) * VV + v0);
        #pragma unroll
        for (int j = 0; j < 4; ++j) od[j] = es[j];
    }
}

__global__ void vq_entropy(const unsigned int* __restrict__ hist, float* __restrict__ out_ent) {
    __shared__ float partial[16];
    int t = threadIdx.x;                 // 1024 threads = 16 waves
    unsigned int c = hist[t];
    float p = (float)c * (1.0f / (float)NS);
    float e = (c > 0u) ? -p * logf(p) : 0.f;
    #pragma unroll
    for (int off = 32; off > 0; off >>= 1) e += __shfl_down(e, off, 64);
    if ((t & 63) == 0) partial[t >> 6] = e;
    __syncthreads();
    if (t < 16) {
        float v = partial[t];
        #pragma unroll
        for (int off = 8; off > 0; off >>= 1) v += __shfl_down(v, off, 64);
        if (t == 0) out_ent[0] = v;
    }
}

extern "C" void kernel_launch(void* const* d_in, const int* in_sizes, int n_in,
                              void* d_out, int out_size, void* d_ws, size_t ws_size,
                              hipStream_t stream) {
    const float* x   = (const float*)d_in[0];   // (8,8192,1,64) fp32
    const float* emb = (const float*)d_in[1];   // (1,1024,64) fp32
    float* out = (float*)d_out;                 // out0 | out1 | out2 | entropy
    unsigned int* hist  = (unsigned int*)d_ws;
    float*        enorm = (float*)((char*)d_ws + 4096);

    vq_prep<<<4, 256, 0, stream>>>(emb, hist, enorm);
    vq_main<<<NS / SPB, 256, 0, stream>>>(x, emb, enorm,
                                          out + OUT0_OFF,
                                          out + OUT1_OFF,
                                          out + OUT2_OFF,
                                          hist);
    vq_entropy<<<1, 1024, 0, stream>>>(hist, out + ENT_OFF);
}

// Round 3
// 164.342 us; speedup vs baseline: 3.4649x; 3.4649x over previous
//
#include <hip/hip_runtime.h>
#include <math.h>

// Problem constants: N=8, S=8192, C=1, K=1024, V=64
#define NS  65536            // samples
#define KK  1024             // codebook size
#define VV  64               // vector length
#define SPB 64               // samples per block (4 waves x 16)
#define NT  (KK / 16)        // 64 code-tiles of 16

// Output layout (flat, return order):
#define OUT0_OFF 0           // (8,8192,1,64) = 4,194,304
#define OUT1_OFF 4194304     // (8,8192,1)    =    65,536
#define OUT2_OFF 4259840     // (8,8192,1)    =    65,536
#define ENT_OFF  4325376     // scalar

// ws layout: [0,4K) hist u32; [4K,8K) enorm f32; [8K,8K+128K) bf16 codebook [1024][64]

typedef __attribute__((ext_vector_type(8))) short bf16x8;
typedef __attribute__((ext_vector_type(4))) float f32x4;

__device__ __forceinline__ short f2bf(float f) {
    unsigned u = __float_as_uint(f);
    u = (u + 0x7fffu + ((u >> 16) & 1u)) >> 16;   // RNE
    return (short)u;
}

__global__ void vq_prep(const float* __restrict__ emb, unsigned int* __restrict__ hist,
                        float* __restrict__ enorm, short* __restrict__ cb) {
    int t = blockIdx.x * blockDim.x + threadIdx.x;   // 0..1023 (one code per thread)
    if (t < KK) {
        hist[t] = 0u;
        const float4* e4 = (const float4*)(emb + (size_t)t * VV);
        float s = 0.f;
        union { short sh[8]; bf16x8 v; } pk;
        bf16x8* dst = (bf16x8*)(cb + (size_t)t * VV);
        #pragma unroll
        for (int i = 0; i < 8; ++i) {            // 8 x (2 float4 -> 8 bf16)
            float4 f0 = e4[2 * i], f1 = e4[2 * i + 1];
            s = fmaf(f0.x, f0.x, s); s = fmaf(f0.y, f0.y, s);
            s = fmaf(f0.z, f0.z, s); s = fmaf(f0.w, f0.w, s);
            s = fmaf(f1.x, f1.x, s); s = fmaf(f1.y, f1.y, s);
            s = fmaf(f1.z, f1.z, s); s = fmaf(f1.w, f1.w, s);
            pk.sh[0] = f2bf(f0.x); pk.sh[1] = f2bf(f0.y);
            pk.sh[2] = f2bf(f0.z); pk.sh[3] = f2bf(f0.w);
            pk.sh[4] = f2bf(f1.x); pk.sh[5] = f2bf(f1.y);
            pk.sh[6] = f2bf(f1.z); pk.sh[7] = f2bf(f1.w);
            dst[i] = pk.v;
        }
        enorm[t] = s;
    }
}

__global__ __launch_bounds__(256, 4) void vq_main(
    const float* __restrict__ x, const float* __restrict__ emb,
    const float* __restrict__ enorm, const short* __restrict__ cb,
    float* __restrict__ out0, float* __restrict__ out1, float* __restrict__ out2,
    unsigned int* __restrict__ hist)
{
    __shared__ int cand1[SPB];
    __shared__ int cand2[SPB];
    __shared__ int lbest[SPB];

    const int tid  = threadIdx.x;
    const int wave = tid >> 6;
    const int lane = tid & 63;
    const int col  = lane & 15;      // MFMA "n" (code within tile) / A-row m
    const int quad = lane >> 4;      // k-group
    const int s0   = blockIdx.x * SPB;
    const int mbase = wave * 16;     // this wave's 16-sample tile within the block

    // ---- A fragments: A[m=col][k=quad*8+j], two k-halves (0..31, 32..63) ----
    bf16x8 a0, a1;
    {
        const float* xr = x + (size_t)(s0 + mbase + col) * VV + quad * 8;
        float4 p0 = *(const float4*)(xr);
        float4 p1 = *(const float4*)(xr + 4);
        float4 p2 = *(const float4*)(xr + 32);
        float4 p3 = *(const float4*)(xr + 36);
        a0[0] = f2bf(p0.x); a0[1] = f2bf(p0.y); a0[2] = f2bf(p0.z); a0[3] = f2bf(p0.w);
        a0[4] = f2bf(p1.x); a0[5] = f2bf(p1.y); a0[6] = f2bf(p1.z); a0[7] = f2bf(p1.w);
        a1[0] = f2bf(p2.x); a1[1] = f2bf(p2.y); a1[2] = f2bf(p2.z); a1[3] = f2bf(p2.w);
        a1[4] = f2bf(p3.x); a1[5] = f2bf(p3.y); a1[6] = f2bf(p3.z); a1[7] = f2bf(p3.w);
    }

    // ---- screen all 1024 codes with MFMA, tracking per-lane top-2 per row ----
    float s1[4], s2[4];
    int   i1[4], i2[4];
    #pragma unroll
    for (int r = 0; r < 4; ++r) { s1[r] = INFINITY; s2[r] = INFINITY; i1[r] = 0; i2[r] = 0; }

    #pragma unroll 2
    for (int t = 0; t < NT; ++t) {
        const int code = t * 16 + col;
        const short* rowp = cb + (size_t)code * VV + quad * 8;
        bf16x8 b0 = *(const bf16x8*)rowp;          // k = quad*8..+7
        bf16x8 b1 = *(const bf16x8*)(rowp + 32);   // k = 32+quad*8..+7
        f32x4 acc = {0.f, 0.f, 0.f, 0.f};
        acc = __builtin_amdgcn_mfma_f32_16x16x32_bf16(a0, b0, acc, 0, 0, 0);
        acc = __builtin_amdgcn_mfma_f32_16x16x32_bf16(a1, b1, acc, 0, 0, 0);
        float en = enorm[code];
        #pragma unroll
        for (int r = 0; r < 4; ++r) {
            float sc = fmaf(-2.f, acc[r], en);     // |e|^2 - 2 x.e
            bool c1 = sc < s1[r];
            bool c2 = sc < s2[r];
            s2[r] = fminf(s2[r], fmaxf(s1[r], sc));
            i2[r] = c1 ? i1[r] : (c2 ? code : i2[r]);
            s1[r] = fminf(s1[r], sc);
            i1[r] = c1 ? code : i1[r];
        }
    }

    // ---- merge top-2 across the 16 lanes of each quad-group (samples quad*4+r) ----
    #pragma unroll
    for (int off = 1; off < 16; off <<= 1) {
        #pragma unroll
        for (int r = 0; r < 4; ++r) {
            float o1 = __shfl_xor(s1[r], off, 64);
            int   q1 = __shfl_xor(i1[r], off, 64);
            float o2 = __shfl_xor(s2[r], off, 64);
            int   q2 = __shfl_xor(i2[r], off, 64);
            bool owin = (o1 < s1[r]) || (o1 == s1[r] && q1 < i1[r]);
            if (owin) {
                bool mine2 = (s1[r] < o2) || (s1[r] == o2 && i1[r] < q2);
                s2[r] = mine2 ? s1[r] : o2;
                i2[r] = mine2 ? i1[r] : q2;
                s1[r] = o1; i1[r] = q1;
            } else {
                bool take = (o1 < s2[r]) || (o1 == s2[r] && q1 < i2[r]);
                if (take) { s2[r] = o1; i2[r] = q1; }
            }
        }
    }

    if (col == 0) {
        #pragma unroll
        for (int r = 0; r < 4; ++r) {
            cand1[mbase + quad * 4 + r] = i1[r];
            cand2[mbase + quad * 4 + r] = i2[r];
        }
    }
    __syncthreads();

    // ---- exact fp32 re-rank of the two candidates; emit out1/out2/hist ----
    if (lane < 16) {
        const int m = mbase + lane;
        const int n = s0 + m;
        const int ca = cand1[m], cbn = cand2[m];
        const float4* xr  = (const float4*)(x   + (size_t)n   * VV);
        const float4* e1p = (const float4*)(emb + (size_t)ca  * VV);
        const float4* e2p = (const float4*)(emb + (size_t)cbn * VV);
        float d1 = 0.f, d2v = 0.f;
        #pragma unroll
        for (int i = 0; i < 16; ++i) {
            float4 xv = xr[i], ea = e1p[i], eb = e2p[i];
            float t0 = xv.x - ea.x, t1 = xv.y - ea.y, t2 = xv.z - ea.z, t3 = xv.w - ea.w;
            d1 = fmaf(t0, t0, d1); d1 = fmaf(t1, t1, d1);
            d1 = fmaf(t2, t2, d1); d1 = fmaf(t3, t3, d1);
            float u0 = xv.x - eb.x, u1 = xv.y - eb.y, u2 = xv.z - eb.z, u3 = xv.w - eb.w;
            d2v = fmaf(u0, u0, d2v); d2v = fmaf(u1, u1, d2v);
            d2v = fmaf(u2, u2, d2v); d2v = fmaf(u3, u3, d2v);
        }
        bool second = (d2v < d1) || (d2v == d1 && cbn < ca);
        int best = second ? cbn : ca;
        float db = second ? d2v : d1;
        out1[n] = db;
        out2[n] = db;
        atomicAdd(&hist[best], 1u);
        lbest[m] = best;
    }
    __syncthreads();

    // ---- cooperative coalesced out0 write: 256 threads x 16 contiguous floats ----
    {
        int smp = tid >> 2;
        int v0  = (tid & 3) * 16;
        int row = lbest[smp];
        const float4* es = (const float4*)(emb + (size_t)row * VV + v0);
        float4*       od = (float4*)(out0 + (size_t)(s0 + smp) * VV + v0);
        #pragma unroll
        for (int j = 0; j < 4; ++j) od[j] = es[j];
    }
}

__global__ void vq_entropy(const unsigned int* __restrict__ hist, float* __restrict__ out_ent) {
    __shared__ float partial[16];
    int t = threadIdx.x;                 // 1024 threads = 16 waves
    unsigned int c = hist[t];
    float p = (float)c * (1.0f / (float)NS);
    float e = (c > 0u) ? -p * logf(p) : 0.f;
    #pragma unroll
    for (int off = 32; off > 0; off >>= 1) e += __shfl_down(e, off, 64);
    if ((t & 63) == 0) partial[t >> 6] = e;
    __syncthreads();
    if (t < 16) {
        float v = partial[t];
        #pragma unroll
        for (int off = 8; off > 0; off >>= 1) v += __shfl_down(v, off, 64);
        if (t == 0) out_ent[0] = v;
    }
}

extern "C" void kernel_launch(void* const* d_in, const int* in_sizes, int n_in,
                              void* d_out, int out_size, void* d_ws, size_t ws_size,
                              hipStream_t stream) {
    const float* x   = (const float*)d_in[0];   // (8,8192,1,64) fp32
    const float* emb = (const float*)d_in[1];   // (1,1024,64) fp32
    float* out = (float*)d_out;
    unsigned int* hist  = (unsigned int*)d_ws;
    float*        enorm = (float*)((char*)d_ws + 4096);
    short*        cb    = (short*)((char*)d_ws + 8192);   // bf16 codebook, 128 KB

    vq_prep<<<4, 256, 0, stream>>>(emb, hist, enorm, cb);
    vq_main<<<NS / SPB, 256, 0, stream>>>(x, emb, enorm, cb,
                                          out + OUT0_OFF, out + OUT1_OFF,
                                          out + OUT2_OFF, hist);
    vq_entropy<<<1, 1024, 0, stream>>>(hist, out + ENT_OFF);
}